// Round 6
// baseline (258.023 us; speedup 1.0000x reference)
//
#include <hip/hip_runtime.h>

#define N_NODES 100000
#define N_EDGES 1600000
#define IN_FEAT 128
#define OUT_FEAT 64
#define SLOPE 0.22916666666666666f  // (1/8 + 1/3)/2 = 11/48

#define NPB 128            // nodes per bucket
#define NB 782             // ceil(N_NODES / NPB)
#define BIN_CHUNK 8192     // edges per binning block
#define EPT 32             // edges per thread in binning (BIN_CHUNK/256)

__device__ __forceinline__ ushort f2bf(float x) {
    unsigned u = __float_as_uint(x);
    u += 0x7FFFu + ((u >> 16) & 1u);  // round to nearest even
    return (ushort)(u >> 16);
}
__device__ __forceinline__ float bf2f(ushort v) {
    return __uint_as_float((unsigned)v << 16);
}

// ---------------------------------------------------------------------------
// Bucket histogram: LDS-binned per block, one global atomic per bucket/block.
// ---------------------------------------------------------------------------
__global__ __launch_bounds__(256) void bhist_kernel(const int* __restrict__ dst,
                                                    int* __restrict__ bhist) {
    __shared__ int lh[NB];
    for (int i = threadIdx.x; i < NB; i += 256) lh[i] = 0;
    __syncthreads();
    const int base = blockIdx.x * 2048;
#pragma unroll
    for (int i = 0; i < 8; ++i) {
        const int e = base + i * 256 + threadIdx.x;
        if (e < N_EDGES) atomicAdd(&lh[dst[e] >> 7], 1);
    }
    __syncthreads();
    for (int i = threadIdx.x; i < NB; i += 256)
        if (lh[i]) atomicAdd(&bhist[i], lh[i]);
}

// ---------------------------------------------------------------------------
// Exclusive scan of 782 bucket counts (single block) -> bbase[NB+1], bcur.
// ---------------------------------------------------------------------------
__global__ __launch_bounds__(256) void bscan_kernel(const int* __restrict__ bhist,
                                                    int* __restrict__ bbase,
                                                    int* __restrict__ bcur) {
    __shared__ int wsum[4];
    const int t = threadIdx.x;
    int v[4];
    int s = 0;
#pragma unroll
    for (int i = 0; i < 4; ++i) {
        const int idx = t * 4 + i;
        v[i] = s;
        s += (idx < NB) ? bhist[idx] : 0;
    }
    const int lane = t & 63, wave = t >> 6;
    int x = s;
#pragma unroll
    for (int off = 1; off < 64; off <<= 1) {
        int y = __shfl_up(x, off);
        if (lane >= off) x += y;
    }
    if (lane == 63) wsum[wave] = x;
    __syncthreads();
    int wbase = 0;
    for (int w = 0; w < 4; ++w)
        if (w < wave) wbase += wsum[w];
    const int tbase = wbase + x - s;
#pragma unroll
    for (int i = 0; i < 4; ++i) {
        const int idx = t * 4 + i;
        if (idx < NB) {
            bbase[idx] = tbase + v[i];
            bcur[idx]  = tbase + v[i];
        }
    }
    if (t == 255) bbase[NB] = wbase + x;  // == N_EDGES
}

// ---------------------------------------------------------------------------
// Binning pass 1: dense per-block runs of packed ((dst&127)<<17 | src).
// ---------------------------------------------------------------------------
__global__ __launch_bounds__(256) void binning_kernel(const int* __restrict__ src,
                                                      const int* __restrict__ dst,
                                                      int* __restrict__ bcur,
                                                      int* __restrict__ pairs) {
    __shared__ int cnt[NB];
    __shared__ int gbase[NB];
    for (int i = threadIdx.x; i < NB; i += 256) cnt[i] = 0;
    __syncthreads();
    const int base = blockIdx.x * BIN_CHUNK;
    int bl[EPT];
    int vp[EPT];
#pragma unroll
    for (int i = 0; i < EPT; ++i) {
        const int e = base + i * 256 + threadIdx.x;
        if (e < N_EDGES) {
            const int d = dst[e];
            const int b = d >> 7;
            const int lpos = atomicAdd(&cnt[b], 1);
            bl[i] = (b << 13) | lpos;
            vp[i] = ((d & 127) << 17) | src[e];
        } else {
            bl[i] = -1;
        }
    }
    __syncthreads();
    for (int i = threadIdx.x; i < NB; i += 256) {
        const int c = cnt[i];
        gbase[i] = c ? atomicAdd(&bcur[i], c) : 0;
    }
    __syncthreads();
#pragma unroll
    for (int i = 0; i < EPT; ++i) {
        if (bl[i] >= 0) {
            const int b = bl[i] >> 13, lpos = bl[i] & 8191;
            pairs[gbase[b] + lpos] = vp[i];
        }
    }
}

// ---------------------------------------------------------------------------
// Binning pass 2: per-bucket counting sort -> per-node CSR segments.
// ---------------------------------------------------------------------------
__global__ __launch_bounds__(256) void sort2_kernel(const int* __restrict__ pairs,
                                                    const int* __restrict__ bbase,
                                                    int* __restrict__ csr,
                                                    int* __restrict__ nptr) {
    __shared__ int cnt[NPB];
    __shared__ int cur[NPB];
    __shared__ int wtot;
    const int b = blockIdx.x;
    const int t = threadIdx.x;
    const int beg = bbase[b], end = bbase[b + 1];
    if (t < NPB) cnt[t] = 0;
    __syncthreads();
    for (int i = beg + t; i < end; i += 256)
        atomicAdd(&cnt[pairs[i] >> 17], 1);
    __syncthreads();
    int v = 0, x = 0;
    const int lane = t & 63, w = t >> 6;
    if (t < NPB) {
        v = cnt[t];
        x = v;
#pragma unroll
        for (int off = 1; off < 64; off <<= 1) {
            int y = __shfl_up(x, off);
            if (lane >= off) x += y;
        }
        if (t == 63) wtot = x;
    }
    __syncthreads();
    if (t < NPB) {
        const int gp = beg + (x - v) + (w ? wtot : 0);
        cur[t] = gp;
        nptr[b * NPB + t] = gp;
    }
    if (b == NB - 1 && t == 255) nptr[NB * NPB] = end;
    __syncthreads();
    for (int i = beg + t; i < end; i += 256) {
        const int p = pairs[i];
        const int pos = atomicAdd(&cur[p >> 17], 1);
        csr[pos] = p & 0x1FFFF;
    }
}

// ---------------------------------------------------------------------------
// Dual-stream gather core: 32 lanes per row (ushort2 = 2 cols/lane), two
// edge-streams per wave (halves), interleaved over the node's csr segment.
// 8 rows in flight per stream iteration = 16 edges/wave. Returns the
// half-stream partial in acc; caller merges with shfl_xor(32).
// ---------------------------------------------------------------------------
__device__ __forceinline__ float2 gather_half(const ushort* __restrict__ h,
                                              const int* __restrict__ csr,
                                              int beg, int end, int half, int sl) {
    float2 acc = make_float2(0.f, 0.f);
    int i = beg + half;
    for (; i + 14 < end; i += 16) {
        const int s0 = csr[i],      s1 = csr[i + 2],  s2 = csr[i + 4],  s3 = csr[i + 6];
        const int s4 = csr[i + 8],  s5 = csr[i + 10], s6 = csr[i + 12], s7 = csr[i + 14];
        const ushort2 u0 = ((const ushort2*)(h + (size_t)s0 * OUT_FEAT))[sl];
        const ushort2 u1 = ((const ushort2*)(h + (size_t)s1 * OUT_FEAT))[sl];
        const ushort2 u2 = ((const ushort2*)(h + (size_t)s2 * OUT_FEAT))[sl];
        const ushort2 u3 = ((const ushort2*)(h + (size_t)s3 * OUT_FEAT))[sl];
        const ushort2 u4 = ((const ushort2*)(h + (size_t)s4 * OUT_FEAT))[sl];
        const ushort2 u5 = ((const ushort2*)(h + (size_t)s5 * OUT_FEAT))[sl];
        const ushort2 u6 = ((const ushort2*)(h + (size_t)s6 * OUT_FEAT))[sl];
        const ushort2 u7 = ((const ushort2*)(h + (size_t)s7 * OUT_FEAT))[sl];
        acc.x += ((bf2f(u0.x) + bf2f(u1.x)) + (bf2f(u2.x) + bf2f(u3.x))) +
                 ((bf2f(u4.x) + bf2f(u5.x)) + (bf2f(u6.x) + bf2f(u7.x)));
        acc.y += ((bf2f(u0.y) + bf2f(u1.y)) + (bf2f(u2.y) + bf2f(u3.y))) +
                 ((bf2f(u4.y) + bf2f(u5.y)) + (bf2f(u6.y) + bf2f(u7.y)));
    }
    for (; i < end; i += 2) {
        const ushort2 u = ((const ushort2*)(h + (size_t)csr[i] * OUT_FEAT))[sl];
        acc.x += bf2f(u.x);
        acc.y += bf2f(u.y);
    }
    return acc;
}

// ---------------------------------------------------------------------------
// Layer-1 fused: agg(h1) -> rrelu -> @w2 -> bf16 h2. One wave per node.
// No cross-wave barrier after staging: rowbuf is per-wave, intra-wave LDS
// ordering is handled by compiler lgkmcnt.
// ---------------------------------------------------------------------------
__global__ __launch_bounds__(256) void agg_gemm2_kernel(const ushort* __restrict__ h,
                                                        const int* __restrict__ csr,
                                                        const int* __restrict__ nptr,
                                                        const float* __restrict__ w2,
                                                        ushort* __restrict__ h2) {
    __shared__ float w[OUT_FEAT * OUT_FEAT];  // 16 KB
    __shared__ float rowbuf[4][OUT_FEAT];     // 1 KB, one row per wave
    const int tid = threadIdx.x;

    const float4* w4g = (const float4*)w2;
    float4* wl = (float4*)w;
#pragma unroll
    for (int i = 0; i < 4; ++i) wl[tid + i * 256] = w4g[tid + i * 256];
    __syncthreads();  // w staged (only cross-wave dependency in this kernel)

    const int wv = tid >> 6, c = tid & 63;
    const int half = (tid >> 5) & 1, sl = tid & 31;
    const int node = blockIdx.x * 4 + wv;  // grid = 25000, all valid
    const int beg = nptr[node], end = nptr[node + 1];

    float2 acc = gather_half(h, csr, beg, end, half, sl);
    acc.x += __shfl_xor(acc.x, 32);
    acc.y += __shfl_xor(acc.y, 32);
    acc.x = acc.x >= 0.f ? acc.x : acc.x * SLOPE;
    acc.y = acc.y >= 0.f ? acc.y : acc.y * SLOPE;

    // stage the node's row (intra-wave; no block barrier needed)
    if (half == 0) ((float2*)rowbuf[wv])[sl] = acc;

    float o = 0.f;
    const float4* rb4 = (const float4*)rowbuf[wv];
#pragma unroll
    for (int k = 0; k < OUT_FEAT; k += 4) {
        const float4 r = rb4[k >> 2];  // wave-uniform broadcast
        o += r.x * w[(k + 0) * OUT_FEAT + c] + r.y * w[(k + 1) * OUT_FEAT + c] +
             r.z * w[(k + 2) * OUT_FEAT + c] + r.w * w[(k + 3) * OUT_FEAT + c];
    }
    h2[(size_t)node * OUT_FEAT + c] = f2bf(o);
}

// ---------------------------------------------------------------------------
// Layer-2 aggregation + fused rrelu -> f32 d_out. One wave per node.
// ---------------------------------------------------------------------------
__global__ __launch_bounds__(256) void agg_rrelu_kernel(const ushort* __restrict__ h,
                                                        const int* __restrict__ csr,
                                                        const int* __restrict__ nptr,
                                                        float* __restrict__ out) {
    const int tid = threadIdx.x;
    const int half = (tid >> 5) & 1, sl = tid & 31;
    const int node = blockIdx.x * 4 + (tid >> 6);
    const int beg = nptr[node], end = nptr[node + 1];

    float2 acc = gather_half(h, csr, beg, end, half, sl);
    acc.x += __shfl_xor(acc.x, 32);
    acc.y += __shfl_xor(acc.y, 32);
    if (half == 0) {
        acc.x = acc.x >= 0.f ? acc.x : acc.x * SLOPE;
        acc.y = acc.y >= 0.f ? acc.y : acc.y * SLOPE;
        ((float2*)(out + (size_t)node * OUT_FEAT))[sl] = acc;
    }
}

// ---------------------------------------------------------------------------
// GEMM1: feat[N,128] @ w1[128,64] -> bf16 h. 16 rows/block, 4 rows/thread.
// ---------------------------------------------------------------------------
__global__ __launch_bounds__(256) void gemm1_kernel(const float* __restrict__ feat,
                                                    const float* __restrict__ w1,
                                                    ushort* __restrict__ h1) {
    __shared__ float w[IN_FEAT * OUT_FEAT];  // 32 KB
    __shared__ float f[16 * IN_FEAT];        // 8 KB
    const int tid = threadIdx.x;

    const float4* w4 = (const float4*)w1;
    float4* wl = (float4*)w;
#pragma unroll
    for (int i = 0; i < 8; ++i) wl[tid + i * 256] = w4[tid + i * 256];

    const int row0 = blockIdx.x * 16;
    const float4* fg = (const float4*)(feat + (size_t)row0 * IN_FEAT);
    float4* fl = (float4*)f;
#pragma unroll
    for (int i = 0; i < 2; ++i) fl[tid + i * 256] = fg[tid + i * 256];
    __syncthreads();

    const int c = tid & 63;
    const int rg = tid >> 6;
    float acc0 = 0.f, acc1 = 0.f, acc2 = 0.f, acc3 = 0.f;
    const float4* fv = (const float4*)f;
#pragma unroll
    for (int k = 0; k < IN_FEAT; k += 4) {
        const float wa = w[(k + 0) * OUT_FEAT + c];
        const float wb = w[(k + 1) * OUT_FEAT + c];
        const float wc = w[(k + 2) * OUT_FEAT + c];
        const float wd = w[(k + 3) * OUT_FEAT + c];
        float4 a = fv[((rg * 4 + 0) * IN_FEAT + k) >> 2];
        acc0 += a.x * wa + a.y * wb + a.z * wc + a.w * wd;
        float4 bb = fv[((rg * 4 + 1) * IN_FEAT + k) >> 2];
        acc1 += bb.x * wa + bb.y * wb + bb.z * wc + bb.w * wd;
        float4 d = fv[((rg * 4 + 2) * IN_FEAT + k) >> 2];
        acc2 += d.x * wa + d.y * wb + d.z * wc + d.w * wd;
        float4 e = fv[((rg * 4 + 3) * IN_FEAT + k) >> 2];
        acc3 += e.x * wa + e.y * wb + e.z * wc + e.w * wd;
    }
    h1[(size_t)(row0 + rg * 4 + 0) * OUT_FEAT + c] = f2bf(acc0);
    h1[(size_t)(row0 + rg * 4 + 1) * OUT_FEAT + c] = f2bf(acc1);
    h1[(size_t)(row0 + rg * 4 + 2) * OUT_FEAT + c] = f2bf(acc2);
    h1[(size_t)(row0 + rg * 4 + 3) * OUT_FEAT + c] = f2bf(acc3);
}

extern "C" void kernel_launch(void* const* d_in, const int* in_sizes, int n_in,
                              void* d_out, int out_size, void* d_ws, size_t ws_size,
                              hipStream_t stream) {
    const float* feat = (const float*)d_in[0];
    const int*   src  = (const int*)d_in[1];
    const int*   dst  = (const int*)d_in[2];
    const float* w1   = (const float*)d_in[3];
    const float* w2   = (const float*)d_in[4];
    float* out = (float*)d_out;

    // workspace layout
    ushort* h1    = (ushort*)d_ws;                            // 12.8 MB
    ushort* h2    = h1 + (size_t)N_NODES * OUT_FEAT;          // 12.8 MB
    int*    pairs = (int*)(h2 + (size_t)N_NODES * OUT_FEAT);  // 6.4 MB
    int*    csr   = pairs + N_EDGES;                          // 6.4 MB
    int*    nptr  = csr + N_EDGES;                            // NB*NPB+1
    int*    bhist = nptr + NB * NPB + 1;                      // NB
    int*    bbase = bhist + NB;                               // NB+1
    int*    bcur  = bbase + NB + 1;                           // NB

    // ---- build by-dst CSR (once; reused for both layers) ----
    hipMemsetAsync(bhist, 0, NB * sizeof(int), stream);
    bhist_kernel<<<(N_EDGES + 2047) / 2048, 256, 0, stream>>>(dst, bhist);
    bscan_kernel<<<1, 256, 0, stream>>>(bhist, bbase, bcur);
    binning_kernel<<<(N_EDGES + BIN_CHUNK - 1) / BIN_CHUNK, 256, 0, stream>>>(
        src, dst, bcur, pairs);
    sort2_kernel<<<NB, 256, 0, stream>>>(pairs, bbase, csr, nptr);

    // ---- layer 1 (gemm2 fused into aggregation) ----
    gemm1_kernel<<<N_NODES / 16, 256, 0, stream>>>(feat, w1, h1);
    agg_gemm2_kernel<<<N_NODES / 4, 256, 0, stream>>>(h1, csr, nptr, w2, h2);

    // ---- layer 2 ----
    agg_rrelu_kernel<<<N_NODES / 4, 256, 0, stream>>>(h2, csr, nptr, out);
}

// Round 7
// 212.462 us; speedup vs baseline: 1.2144x; 1.2144x over previous
//
#include <hip/hip_runtime.h>

#define N_NODES 100000
#define N_EDGES 1600000
#define IN_FEAT 128
#define OUT_FEAT 64
#define SLOPE 0.22916666666666666f  // (1/8 + 1/3)/2 = 11/48

#define NPB 128            // nodes per bucket
#define NB 782             // ceil(N_NODES / NPB)
#define CAP 2560           // static bucket capacity (mean 2046, sigma 45 -> 11+ sigma margin)
#define BIN_CHUNK 8192     // edges per binning block
#define EPT 32             // edges per thread in binning (BIN_CHUNK/256)

__device__ __forceinline__ ushort f2bf(float x) {
    unsigned u = __float_as_uint(x);
    u += 0x7FFFu + ((u >> 16) & 1u);  // round to nearest even
    return (ushort)(u >> 16);
}
__device__ __forceinline__ float bf2f(ushort v) {
    return __uint_as_float((unsigned)v << 16);
}

// ---------------------------------------------------------------------------
// Binning: each block takes 8192 edges, assigns local ranks via LDS counters,
// claims one contiguous run per bucket inside the bucket's STATIC window
// [b*CAP, b*CAP+CAP) via one global atomic per non-empty bucket per block.
// Packed payload: ((dst&127)<<17) | src.
// ---------------------------------------------------------------------------
__global__ __launch_bounds__(256) void binning_kernel(const int* __restrict__ src,
                                                      const int* __restrict__ dst,
                                                      int* __restrict__ bcur,
                                                      int* __restrict__ pairs) {
    __shared__ int cnt[NB];
    __shared__ int gbase[NB];
    for (int i = threadIdx.x; i < NB; i += 256) cnt[i] = 0;
    __syncthreads();
    const int base = blockIdx.x * BIN_CHUNK;
    int bl[EPT];  // (bucket<<13) | local_rank, or -1
    int vp[EPT];  // packed payload
#pragma unroll
    for (int i = 0; i < EPT; ++i) {
        const int e = base + i * 256 + threadIdx.x;
        if (e < N_EDGES) {
            const int d = dst[e];
            const int b = d >> 7;
            const int lpos = atomicAdd(&cnt[b], 1);
            bl[i] = (b << 13) | lpos;
            vp[i] = ((d & 127) << 17) | src[e];
        } else {
            bl[i] = -1;
        }
    }
    __syncthreads();
    for (int i = threadIdx.x; i < NB; i += 256) {
        const int c = cnt[i];
        gbase[i] = c ? (i * CAP + atomicAdd(&bcur[i], c)) : 0;
    }
    __syncthreads();
#pragma unroll
    for (int i = 0; i < EPT; ++i) {
        if (bl[i] >= 0) {
            const int b = bl[i] >> 13, lpos = bl[i] & 8191;
            pairs[gbase[b] + lpos] = vp[i];
        }
    }
}

// ---------------------------------------------------------------------------
// Per-bucket counting sort -> per-node CSR segments (within static windows).
// Emits per-node {beg,end} (int2), so inter-window gaps are harmless.
// ---------------------------------------------------------------------------
__global__ __launch_bounds__(256) void sort2_kernel(const int* __restrict__ pairs,
                                                    const int* __restrict__ bcur,
                                                    int* __restrict__ csr,
                                                    int2* __restrict__ nseg) {
    __shared__ int cnt[NPB];
    __shared__ int cur[NPB];
    __shared__ int wtot;
    const int b = blockIdx.x;
    const int t = threadIdx.x;
    const int beg = b * CAP;
    const int end = beg + bcur[b];
    if (t < NPB) cnt[t] = 0;
    __syncthreads();
    for (int i = beg + t; i < end; i += 256)
        atomicAdd(&cnt[pairs[i] >> 17], 1);
    __syncthreads();
    int v = 0, x = 0;
    const int lane = t & 63, w = t >> 6;
    if (t < NPB) {
        v = cnt[t];
        x = v;
#pragma unroll
        for (int off = 1; off < 64; off <<= 1) {
            int y = __shfl_up(x, off);
            if (lane >= off) x += y;
        }
        if (t == 63) wtot = x;
    }
    __syncthreads();
    if (t < NPB) {
        const int gp = beg + (x - v) + (w ? wtot : 0);
        cur[t] = gp;
        nseg[b * NPB + t] = make_int2(gp, gp + v);
    }
    __syncthreads();
    for (int i = beg + t; i < end; i += 256) {
        const int p = pairs[i];
        const int pos = atomicAdd(&cur[p >> 17], 1);
        csr[pos] = p & 0x1FFFF;
    }
}

// gather-accumulate: 8-deep unrolled row-gather, lane = column (64 lanes/row)
#define GATHER8(acc)                                                        \
    {                                                                       \
        const int s0 = csr[i], s1 = csr[i + 1], s2 = csr[i + 2],            \
                  s3 = csr[i + 3], s4 = csr[i + 4], s5 = csr[i + 5],        \
                  s6 = csr[i + 6], s7 = csr[i + 7];                         \
        const float v0 = bf2f(h[(size_t)s0 * OUT_FEAT + c]);                \
        const float v1 = bf2f(h[(size_t)s1 * OUT_FEAT + c]);                \
        const float v2 = bf2f(h[(size_t)s2 * OUT_FEAT + c]);                \
        const float v3 = bf2f(h[(size_t)s3 * OUT_FEAT + c]);                \
        const float v4 = bf2f(h[(size_t)s4 * OUT_FEAT + c]);                \
        const float v5 = bf2f(h[(size_t)s5 * OUT_FEAT + c]);                \
        const float v6 = bf2f(h[(size_t)s6 * OUT_FEAT + c]);                \
        const float v7 = bf2f(h[(size_t)s7 * OUT_FEAT + c]);                \
        acc += ((v0 + v1) + (v2 + v3)) + ((v4 + v5) + (v6 + v7));           \
    }

// ---------------------------------------------------------------------------
// Layer-1 fused: agg(h1) -> rrelu -> @w2 -> bf16 h2. One wave per node,
// lane = column. rowbuf is per-wave; intra-wave LDS ordering handled by
// compiler lgkmcnt, so no barrier after staging.
// ---------------------------------------------------------------------------
__global__ __launch_bounds__(256) void agg_gemm2_kernel(const ushort* __restrict__ h,
                                                        const int* __restrict__ csr,
                                                        const int2* __restrict__ nseg,
                                                        const float* __restrict__ w2,
                                                        ushort* __restrict__ h2) {
    __shared__ float w[OUT_FEAT * OUT_FEAT];  // 16 KB
    __shared__ float rowbuf[4][OUT_FEAT];     // 1 KB, one row per wave
    const int tid = threadIdx.x;

    const float4* w4g = (const float4*)w2;
    float4* wl = (float4*)w;
#pragma unroll
    for (int i = 0; i < 4; ++i) wl[tid + i * 256] = w4g[tid + i * 256];
    __syncthreads();  // w staged (only cross-wave dependency)

    const int wv = tid >> 6, c = tid & 63;
    const int node = blockIdx.x * 4 + wv;  // grid = 25000, all valid
    const int2 seg = nseg[node];
    const int beg = seg.x, end = seg.y;
    float acc = 0.f;
    int i = beg;
    for (; i + 8 <= end; i += 8) GATHER8(acc);
    if (i + 4 <= end) {
        const int s0 = csr[i], s1 = csr[i + 1], s2 = csr[i + 2], s3 = csr[i + 3];
        acc += (bf2f(h[(size_t)s0 * OUT_FEAT + c]) + bf2f(h[(size_t)s1 * OUT_FEAT + c])) +
               (bf2f(h[(size_t)s2 * OUT_FEAT + c]) + bf2f(h[(size_t)s3 * OUT_FEAT + c]));
        i += 4;
    }
    for (; i < end; ++i) acc += bf2f(h[(size_t)csr[i] * OUT_FEAT + c]);
    acc = acc >= 0.f ? acc : acc * SLOPE;

    rowbuf[wv][c] = acc;  // intra-wave only; no block barrier needed

    float o = 0.f;
    const float4* rb4 = (const float4*)rowbuf[wv];
#pragma unroll
    for (int k = 0; k < OUT_FEAT; k += 4) {
        const float4 r = rb4[k >> 2];  // wave-uniform broadcast
        o += r.x * w[(k + 0) * OUT_FEAT + c] + r.y * w[(k + 1) * OUT_FEAT + c] +
             r.z * w[(k + 2) * OUT_FEAT + c] + r.w * w[(k + 3) * OUT_FEAT + c];
    }
    h2[(size_t)node * OUT_FEAT + c] = f2bf(o);
}

// ---------------------------------------------------------------------------
// Layer-2 aggregation + fused rrelu -> f32 d_out. One wave per node.
// ---------------------------------------------------------------------------
__global__ __launch_bounds__(256) void agg_rrelu_kernel(const ushort* __restrict__ h,
                                                        const int* __restrict__ csr,
                                                        const int2* __restrict__ nseg,
                                                        float* __restrict__ out) {
    const int node = blockIdx.x * 4 + (threadIdx.x >> 6);
    const int c = threadIdx.x & 63;
    const int2 seg = nseg[node];
    const int beg = seg.x, end = seg.y;
    float acc = 0.f;
    int i = beg;
    for (; i + 8 <= end; i += 8) GATHER8(acc);
    if (i + 4 <= end) {
        const int s0 = csr[i], s1 = csr[i + 1], s2 = csr[i + 2], s3 = csr[i + 3];
        acc += (bf2f(h[(size_t)s0 * OUT_FEAT + c]) + bf2f(h[(size_t)s1 * OUT_FEAT + c])) +
               (bf2f(h[(size_t)s2 * OUT_FEAT + c]) + bf2f(h[(size_t)s3 * OUT_FEAT + c]));
        i += 4;
    }
    for (; i < end; ++i) acc += bf2f(h[(size_t)csr[i] * OUT_FEAT + c]);
    acc = acc >= 0.f ? acc : acc * SLOPE;
    out[(size_t)node * OUT_FEAT + c] = acc;
}

// ---------------------------------------------------------------------------
// GEMM1: feat[N,128] @ w1[128,64] -> bf16 h. 16 rows/block, 4 rows/thread.
// ---------------------------------------------------------------------------
__global__ __launch_bounds__(256) void gemm1_kernel(const float* __restrict__ feat,
                                                    const float* __restrict__ w1,
                                                    ushort* __restrict__ h1) {
    __shared__ float w[IN_FEAT * OUT_FEAT];  // 32 KB
    __shared__ float f[16 * IN_FEAT];        // 8 KB
    const int tid = threadIdx.x;

    const float4* w4 = (const float4*)w1;
    float4* wl = (float4*)w;
#pragma unroll
    for (int i = 0; i < 8; ++i) wl[tid + i * 256] = w4[tid + i * 256];

    const int row0 = blockIdx.x * 16;
    const float4* fg = (const float4*)(feat + (size_t)row0 * IN_FEAT);
    float4* fl = (float4*)f;
#pragma unroll
    for (int i = 0; i < 2; ++i) fl[tid + i * 256] = fg[tid + i * 256];
    __syncthreads();

    const int c = tid & 63;
    const int rg = tid >> 6;
    float acc0 = 0.f, acc1 = 0.f, acc2 = 0.f, acc3 = 0.f;
    const float4* fv = (const float4*)f;
#pragma unroll
    for (int k = 0; k < IN_FEAT; k += 4) {
        const float wa = w[(k + 0) * OUT_FEAT + c];
        const float wb = w[(k + 1) * OUT_FEAT + c];
        const float wc = w[(k + 2) * OUT_FEAT + c];
        const float wd = w[(k + 3) * OUT_FEAT + c];
        float4 a = fv[((rg * 4 + 0) * IN_FEAT + k) >> 2];
        acc0 += a.x * wa + a.y * wb + a.z * wc + a.w * wd;
        float4 bb = fv[((rg * 4 + 1) * IN_FEAT + k) >> 2];
        acc1 += bb.x * wa + bb.y * wb + bb.z * wc + bb.w * wd;
        float4 d = fv[((rg * 4 + 2) * IN_FEAT + k) >> 2];
        acc2 += d.x * wa + d.y * wb + d.z * wc + d.w * wd;
        float4 e = fv[((rg * 4 + 3) * IN_FEAT + k) >> 2];
        acc3 += e.x * wa + e.y * wb + e.z * wc + e.w * wd;
    }
    h1[(size_t)(row0 + rg * 4 + 0) * OUT_FEAT + c] = f2bf(acc0);
    h1[(size_t)(row0 + rg * 4 + 1) * OUT_FEAT + c] = f2bf(acc1);
    h1[(size_t)(row0 + rg * 4 + 2) * OUT_FEAT + c] = f2bf(acc2);
    h1[(size_t)(row0 + rg * 4 + 3) * OUT_FEAT + c] = f2bf(acc3);
}

extern "C" void kernel_launch(void* const* d_in, const int* in_sizes, int n_in,
                              void* d_out, int out_size, void* d_ws, size_t ws_size,
                              hipStream_t stream) {
    const float* feat = (const float*)d_in[0];
    const int*   src  = (const int*)d_in[1];
    const int*   dst  = (const int*)d_in[2];
    const float* w1   = (const float*)d_in[3];
    const float* w2   = (const float*)d_in[4];
    float* out = (float*)d_out;

    // workspace layout (pairs aliases h2: pairs is dead before h2 is written)
    ushort* h1   = (ushort*)d_ws;                             // 12.8 MB
    ushort* h2   = h1 + (size_t)N_NODES * OUT_FEAT;           // 12.8 MB
    int*    pairs = (int*)h2;                                 // 8.0 MB (alias)
    int*    csr  = (int*)(h2 + (size_t)N_NODES * OUT_FEAT);   // NB*CAP = 8.0 MB
    int2*   nseg = (int2*)(csr + NB * CAP);                   // 0.8 MB
    int*    bcur = (int*)(nseg + NB * NPB);                   // NB

    // ---- build by-dst CSR (once; reused for both layers) ----
    hipMemsetAsync(bcur, 0, NB * sizeof(int), stream);
    binning_kernel<<<(N_EDGES + BIN_CHUNK - 1) / BIN_CHUNK, 256, 0, stream>>>(
        src, dst, bcur, pairs);
    sort2_kernel<<<NB, 256, 0, stream>>>(pairs, bcur, csr, nseg);

    // ---- layer 1 (gemm2 fused into aggregation) ----
    gemm1_kernel<<<N_NODES / 16, 256, 0, stream>>>(feat, w1, h1);
    agg_gemm2_kernel<<<N_NODES / 4, 256, 0, stream>>>(h1, csr, nseg, w2, h2);

    // ---- layer 2 ----
    agg_rrelu_kernel<<<N_NODES / 4, 256, 0, stream>>>(h2, csr, nseg, out);
}

// Round 8
// 181.388 us; speedup vs baseline: 1.4225x; 1.1713x over previous
//
#include <hip/hip_runtime.h>

#define N_NODES 100000
#define N_EDGES 1600000
#define IN_FEAT 128
#define OUT_FEAT 64
#define SLOPE 0.22916666666666666f  // (1/8 + 1/3)/2 = 11/48

#define NPB 128            // nodes per bucket
#define NB 782             // ceil(N_NODES / NPB)
#define CAP 2560           // static bucket capacity (mean 2046 -> 11+ sigma margin)
#define BIN_CHUNK 8192     // edges per binning block
#define EPT 32             // edges per thread in binning (BIN_CHUNK/256)
#define BIN_BLOCKS ((N_EDGES + BIN_CHUNK - 1) / BIN_CHUNK)  // 196
#define GEMM1_BLOCKS (N_NODES / 16)                         // 6250

__device__ __forceinline__ ushort f2bf(float x) {
    unsigned u = __float_as_uint(x);
    u += 0x7FFFu + ((u >> 16) & 1u);  // round to nearest even
    return (ushort)(u >> 16);
}
__device__ __forceinline__ float bf2f(ushort v) {
    return __uint_as_float((unsigned)v << 16);
}

// ---------------------------------------------------------------------------
// Fat kernel: blocks [0, BIN_BLOCKS) do edge binning; the rest do gemm1.
// The two jobs are independent (binning reads src/dst, gemm1 reads feat/w1),
// so fusing hides the binning latency under the HBM-bound gemm1.
// ---------------------------------------------------------------------------
union FatSmem {
    struct { float w[IN_FEAT * OUT_FEAT]; float f[16 * IN_FEAT]; } g;  // 40 KB
    struct { int cnt[NB]; int gbase[NB]; } b;                          // 6.3 KB
};

__global__ __launch_bounds__(256) void gemm1_binning_kernel(
        const float* __restrict__ feat, const float* __restrict__ w1,
        ushort* __restrict__ h1,
        const int* __restrict__ src, const int* __restrict__ dst,
        int* __restrict__ bcur, int* __restrict__ pairs) {
    __shared__ FatSmem s;
    const int tid = threadIdx.x;

    if (blockIdx.x >= BIN_BLOCKS) {
        // ---------------- gemm1: feat[16 rows] @ w1 -> bf16 h1 ----------------
        float* w = s.g.w;
        float* f = s.g.f;
        const float4* w4 = (const float4*)w1;
        float4* wl = (float4*)w;
#pragma unroll
        for (int i = 0; i < 8; ++i) wl[tid + i * 256] = w4[tid + i * 256];

        const int row0 = (blockIdx.x - BIN_BLOCKS) * 16;
        const float4* fg = (const float4*)(feat + (size_t)row0 * IN_FEAT);
        float4* fl = (float4*)f;
#pragma unroll
        for (int i = 0; i < 2; ++i) fl[tid + i * 256] = fg[tid + i * 256];
        __syncthreads();

        const int c = tid & 63;
        const int rg = tid >> 6;
        float acc0 = 0.f, acc1 = 0.f, acc2 = 0.f, acc3 = 0.f;
        const float4* fv = (const float4*)f;
#pragma unroll
        for (int k = 0; k < IN_FEAT; k += 4) {
            const float wa = w[(k + 0) * OUT_FEAT + c];
            const float wb = w[(k + 1) * OUT_FEAT + c];
            const float wc = w[(k + 2) * OUT_FEAT + c];
            const float wd = w[(k + 3) * OUT_FEAT + c];
            float4 a = fv[((rg * 4 + 0) * IN_FEAT + k) >> 2];
            acc0 += a.x * wa + a.y * wb + a.z * wc + a.w * wd;
            float4 bb = fv[((rg * 4 + 1) * IN_FEAT + k) >> 2];
            acc1 += bb.x * wa + bb.y * wb + bb.z * wc + bb.w * wd;
            float4 d = fv[((rg * 4 + 2) * IN_FEAT + k) >> 2];
            acc2 += d.x * wa + d.y * wb + d.z * wc + d.w * wd;
            float4 e = fv[((rg * 4 + 3) * IN_FEAT + k) >> 2];
            acc3 += e.x * wa + e.y * wb + e.z * wc + e.w * wd;
        }
        h1[(size_t)(row0 + rg * 4 + 0) * OUT_FEAT + c] = f2bf(acc0);
        h1[(size_t)(row0 + rg * 4 + 1) * OUT_FEAT + c] = f2bf(acc1);
        h1[(size_t)(row0 + rg * 4 + 2) * OUT_FEAT + c] = f2bf(acc2);
        h1[(size_t)(row0 + rg * 4 + 3) * OUT_FEAT + c] = f2bf(acc3);
    } else {
        // ---------------- binning: dense per-block runs per bucket ----------------
        int* cnt = s.b.cnt;
        int* gbase = s.b.gbase;
        for (int i = tid; i < NB; i += 256) cnt[i] = 0;
        __syncthreads();
        const int base = blockIdx.x * BIN_CHUNK;
        int bl[EPT];  // (bucket<<13) | local_rank, or -1
        int vp[EPT];  // packed payload ((dst&127)<<17 | src)
#pragma unroll
        for (int i = 0; i < EPT; ++i) {
            const int e = base + i * 256 + tid;
            if (e < N_EDGES) {
                const int d = dst[e];
                const int b = d >> 7;
                const int lpos = atomicAdd(&cnt[b], 1);
                bl[i] = (b << 13) | lpos;
                vp[i] = ((d & 127) << 17) | src[e];
            } else {
                bl[i] = -1;
            }
        }
        __syncthreads();
        for (int i = tid; i < NB; i += 256) {
            const int c = cnt[i];
            gbase[i] = c ? (i * CAP + atomicAdd(&bcur[i], c)) : 0;
        }
        __syncthreads();
#pragma unroll
        for (int i = 0; i < EPT; ++i) {
            if (bl[i] >= 0) {
                const int b = bl[i] >> 13, lpos = bl[i] & 8191;
                pairs[gbase[b] + lpos] = vp[i];
            }
        }
    }
}

// ---------------------------------------------------------------------------
// Per-bucket counting sort -> per-node CSR segments (within static windows).
// csr entries are PRE-MULTIPLIED element offsets (src*64) to shorten the
// gather address path. Emits per-node {beg,end}.
// ---------------------------------------------------------------------------
__global__ __launch_bounds__(256) void sort2_kernel(const int* __restrict__ pairs,
                                                    const int* __restrict__ bcur,
                                                    int* __restrict__ csr,
                                                    int2* __restrict__ nseg) {
    __shared__ int cnt[NPB];
    __shared__ int cur[NPB];
    __shared__ int wtot;
    const int b = blockIdx.x;
    const int t = threadIdx.x;
    const int beg = b * CAP;
    const int end = beg + bcur[b];
    if (t < NPB) cnt[t] = 0;
    __syncthreads();
    for (int i = beg + t; i < end; i += 256)
        atomicAdd(&cnt[pairs[i] >> 17], 1);
    __syncthreads();
    int v = 0, x = 0;
    const int lane = t & 63, w = t >> 6;
    if (t < NPB) {
        v = cnt[t];
        x = v;
#pragma unroll
        for (int off = 1; off < 64; off <<= 1) {
            int y = __shfl_up(x, off);
            if (lane >= off) x += y;
        }
        if (t == 63) wtot = x;
    }
    __syncthreads();
    if (t < NPB) {
        const int gp = beg + (x - v) + (w ? wtot : 0);
        cur[t] = gp;
        nseg[b * NPB + t] = make_int2(gp, gp + v);
    }
    __syncthreads();
    for (int i = beg + t; i < end; i += 256) {
        const int p = pairs[i];
        const int pos = atomicAdd(&cur[p >> 17], 1);
        csr[pos] = (p & 0x1FFFF) << 6;  // element offset of the src row
    }
}

// gather-accumulate ladder over premultiplied offsets, lane = column
#define G16(acc)                                                            \
    {                                                                       \
        const int o0 = csr[i],      o1 = csr[i + 1],  o2 = csr[i + 2],      \
                  o3 = csr[i + 3],  o4 = csr[i + 4],  o5 = csr[i + 5],      \
                  o6 = csr[i + 6],  o7 = csr[i + 7],  o8 = csr[i + 8],      \
                  o9 = csr[i + 9],  oa = csr[i + 10], ob = csr[i + 11],     \
                  oc = csr[i + 12], od = csr[i + 13], oe = csr[i + 14],     \
                  of_ = csr[i + 15];                                        \
        acc += (((bf2f(h[o0 + c]) + bf2f(h[o1 + c])) +                      \
                 (bf2f(h[o2 + c]) + bf2f(h[o3 + c]))) +                     \
                ((bf2f(h[o4 + c]) + bf2f(h[o5 + c])) +                      \
                 (bf2f(h[o6 + c]) + bf2f(h[o7 + c])))) +                    \
               (((bf2f(h[o8 + c]) + bf2f(h[o9 + c])) +                      \
                 (bf2f(h[oa + c]) + bf2f(h[ob + c]))) +                     \
                ((bf2f(h[oc + c]) + bf2f(h[od + c])) +                      \
                 (bf2f(h[oe + c]) + bf2f(h[of_ + c]))));                    \
    }
#define G8(acc)                                                             \
    {                                                                       \
        const int o0 = csr[i], o1 = csr[i + 1], o2 = csr[i + 2],            \
                  o3 = csr[i + 3], o4 = csr[i + 4], o5 = csr[i + 5],        \
                  o6 = csr[i + 6], o7 = csr[i + 7];                         \
        acc += ((bf2f(h[o0 + c]) + bf2f(h[o1 + c])) +                       \
                (bf2f(h[o2 + c]) + bf2f(h[o3 + c]))) +                      \
               ((bf2f(h[o4 + c]) + bf2f(h[o5 + c])) +                       \
                (bf2f(h[o6 + c]) + bf2f(h[o7 + c])));                       \
    }
#define G4(acc)                                                             \
    {                                                                       \
        const int o0 = csr[i], o1 = csr[i + 1], o2 = csr[i + 2],            \
                  o3 = csr[i + 3];                                          \
        acc += (bf2f(h[o0 + c]) + bf2f(h[o1 + c])) +                        \
               (bf2f(h[o2 + c]) + bf2f(h[o3 + c]));                         \
    }

__device__ __forceinline__ float gather_node(const ushort* __restrict__ h,
                                             const int* __restrict__ csr,
                                             int beg, int end, int c) {
    float acc = 0.f;
    int i = beg;
    for (; i + 16 <= end; i += 16) G16(acc);
    if (i + 8 <= end) { G8(acc); i += 8; }
    if (i + 4 <= end) { G4(acc); i += 4; }
    for (; i < end; ++i) acc += bf2f(h[csr[i] + c]);
    return acc;
}

// ---------------------------------------------------------------------------
// Layer-1 fused: agg(h1) -> rrelu -> @w2 -> bf16 h2. One wave per node.
// rowbuf is per-wave; intra-wave LDS ordering handled by compiler lgkmcnt.
// ---------------------------------------------------------------------------
__global__ __launch_bounds__(256) void agg_gemm2_kernel(const ushort* __restrict__ h,
                                                        const int* __restrict__ csr,
                                                        const int2* __restrict__ nseg,
                                                        const float* __restrict__ w2,
                                                        ushort* __restrict__ h2) {
    __shared__ float w[OUT_FEAT * OUT_FEAT];  // 16 KB
    __shared__ float rowbuf[4][OUT_FEAT];     // 1 KB, one row per wave
    const int tid = threadIdx.x;

    const float4* w4g = (const float4*)w2;
    float4* wl = (float4*)w;
#pragma unroll
    for (int i = 0; i < 4; ++i) wl[tid + i * 256] = w4g[tid + i * 256];
    __syncthreads();  // w staged (only cross-wave dependency)

    const int wv = tid >> 6, c = tid & 63;
    const int node = blockIdx.x * 4 + wv;  // grid = 25000, all valid
    const int2 seg = nseg[node];
    float acc = gather_node(h, csr, seg.x, seg.y, c);
    acc = acc >= 0.f ? acc : acc * SLOPE;

    rowbuf[wv][c] = acc;  // intra-wave only; no block barrier needed

    float o = 0.f;
    const float4* rb4 = (const float4*)rowbuf[wv];
#pragma unroll
    for (int k = 0; k < OUT_FEAT; k += 4) {
        const float4 r = rb4[k >> 2];  // wave-uniform broadcast
        o += r.x * w[(k + 0) * OUT_FEAT + c] + r.y * w[(k + 1) * OUT_FEAT + c] +
             r.z * w[(k + 2) * OUT_FEAT + c] + r.w * w[(k + 3) * OUT_FEAT + c];
    }
    h2[(size_t)node * OUT_FEAT + c] = f2bf(o);
}

// ---------------------------------------------------------------------------
// Layer-2 aggregation + fused rrelu -> f32 d_out. One wave per node.
// ---------------------------------------------------------------------------
__global__ __launch_bounds__(256) void agg_rrelu_kernel(const ushort* __restrict__ h,
                                                        const int* __restrict__ csr,
                                                        const int2* __restrict__ nseg,
                                                        float* __restrict__ out) {
    const int node = blockIdx.x * 4 + (threadIdx.x >> 6);
    const int c = threadIdx.x & 63;
    const int2 seg = nseg[node];
    float acc = gather_node(h, csr, seg.x, seg.y, c);
    acc = acc >= 0.f ? acc : acc * SLOPE;
    out[(size_t)node * OUT_FEAT + c] = acc;
}

extern "C" void kernel_launch(void* const* d_in, const int* in_sizes, int n_in,
                              void* d_out, int out_size, void* d_ws, size_t ws_size,
                              hipStream_t stream) {
    const float* feat = (const float*)d_in[0];
    const int*   src  = (const int*)d_in[1];
    const int*   dst  = (const int*)d_in[2];
    const float* w1   = (const float*)d_in[3];
    const float* w2   = (const float*)d_in[4];
    float* out = (float*)d_out;

    // workspace layout (pairs aliases h2: pairs is dead before h2 is written)
    ushort* h1   = (ushort*)d_ws;                             // 12.8 MB
    ushort* h2   = h1 + (size_t)N_NODES * OUT_FEAT;           // 12.8 MB
    int*    pairs = (int*)h2;                                 // 8.0 MB (alias)
    int*    csr  = (int*)(h2 + (size_t)N_NODES * OUT_FEAT);   // NB*CAP = 8.0 MB
    int2*   nseg = (int2*)(csr + NB * CAP);                   // 0.8 MB
    int*    bcur = (int*)(nseg + NB * NPB);                   // NB

    // ---- build CSR + gemm1 (independent; fused fat kernel) ----
    hipMemsetAsync(bcur, 0, NB * sizeof(int), stream);
    gemm1_binning_kernel<<<BIN_BLOCKS + GEMM1_BLOCKS, 256, 0, stream>>>(
        feat, w1, h1, src, dst, bcur, pairs);
    sort2_kernel<<<NB, 256, 0, stream>>>(pairs, bcur, csr, nseg);

    // ---- layer 1 (gemm2 fused into aggregation) ----
    agg_gemm2_kernel<<<N_NODES / 4, 256, 0, stream>>>(h1, csr, nseg, w2, h2);

    // ---- layer 2 ----
    agg_rrelu_kernel<<<N_NODES / 4, 256, 0, stream>>>(h2, csr, nseg, out);
}

// Round 9
// 174.763 us; speedup vs baseline: 1.4764x; 1.0379x over previous
//
#include <hip/hip_runtime.h>

#define N_NODES 100000
#define N_EDGES 1600000
#define IN_FEAT 128
#define OUT_FEAT 64
#define SLOPE 0.22916666666666666f  // (1/8 + 1/3)/2 = 11/48

#define NPB 128            // nodes per bucket
#define NB 782             // ceil(N_NODES / NPB)
#define CAP 2560           // static bucket capacity (mean 2046 -> 11+ sigma margin)
#define BIN_CHUNK 8192     // edges per binning block
#define EPT 32             // edges per thread in binning (BIN_CHUNK/256)
#define BIN_BLOCKS ((N_EDGES + BIN_CHUNK - 1) / BIN_CHUNK)  // 196
#define GEMM1_BLOCKS (N_NODES / 16)                         // 6250

__device__ __forceinline__ ushort f2bf(float x) {
    unsigned u = __float_as_uint(x);
    u += 0x7FFFu + ((u >> 16) & 1u);  // round to nearest even
    return (ushort)(u >> 16);
}

// ---------------------------------------------------------------------------
// Fat kernel: blocks [0, BIN_BLOCKS) do edge binning; the rest do gemm1.
// ---------------------------------------------------------------------------
union FatSmem {
    struct { float w[IN_FEAT * OUT_FEAT]; float f[16 * IN_FEAT]; } g;  // 40 KB
    struct { int cnt[NB]; int gbase[NB]; } b;                          // 6.3 KB
};

__global__ __launch_bounds__(256) void gemm1_binning_kernel(
        const float* __restrict__ feat, const float* __restrict__ w1,
        ushort* __restrict__ h1,
        const int* __restrict__ src, const int* __restrict__ dst,
        int* __restrict__ bcur, int* __restrict__ pairs) {
    __shared__ FatSmem s;
    const int tid = threadIdx.x;

    if (blockIdx.x >= BIN_BLOCKS) {
        // ---------------- gemm1: feat[16 rows] @ w1 -> bf16 h1 ----------------
        float* w = s.g.w;
        float* f = s.g.f;
        const float4* w4 = (const float4*)w1;
        float4* wl = (float4*)w;
#pragma unroll
        for (int i = 0; i < 8; ++i) wl[tid + i * 256] = w4[tid + i * 256];

        const int row0 = (blockIdx.x - BIN_BLOCKS) * 16;
        const float4* fg = (const float4*)(feat + (size_t)row0 * IN_FEAT);
        float4* fl = (float4*)f;
#pragma unroll
        for (int i = 0; i < 2; ++i) fl[tid + i * 256] = fg[tid + i * 256];
        __syncthreads();

        const int c = tid & 63;
        const int rg = tid >> 6;
        float acc0 = 0.f, acc1 = 0.f, acc2 = 0.f, acc3 = 0.f;
        const float4* fv = (const float4*)f;
#pragma unroll
        for (int k = 0; k < IN_FEAT; k += 4) {
            const float wa = w[(k + 0) * OUT_FEAT + c];
            const float wb = w[(k + 1) * OUT_FEAT + c];
            const float wc = w[(k + 2) * OUT_FEAT + c];
            const float wd = w[(k + 3) * OUT_FEAT + c];
            float4 a = fv[((rg * 4 + 0) * IN_FEAT + k) >> 2];
            acc0 += a.x * wa + a.y * wb + a.z * wc + a.w * wd;
            float4 bb = fv[((rg * 4 + 1) * IN_FEAT + k) >> 2];
            acc1 += bb.x * wa + bb.y * wb + bb.z * wc + bb.w * wd;
            float4 d = fv[((rg * 4 + 2) * IN_FEAT + k) >> 2];
            acc2 += d.x * wa + d.y * wb + d.z * wc + d.w * wd;
            float4 e = fv[((rg * 4 + 3) * IN_FEAT + k) >> 2];
            acc3 += e.x * wa + e.y * wb + e.z * wc + e.w * wd;
        }
        h1[(size_t)(row0 + rg * 4 + 0) * OUT_FEAT + c] = f2bf(acc0);
        h1[(size_t)(row0 + rg * 4 + 1) * OUT_FEAT + c] = f2bf(acc1);
        h1[(size_t)(row0 + rg * 4 + 2) * OUT_FEAT + c] = f2bf(acc2);
        h1[(size_t)(row0 + rg * 4 + 3) * OUT_FEAT + c] = f2bf(acc3);
    } else {
        // ---------------- binning: dense per-block runs per bucket ----------------
        int* cnt = s.b.cnt;
        int* gbase = s.b.gbase;
        for (int i = tid; i < NB; i += 256) cnt[i] = 0;
        __syncthreads();
        const int base = blockIdx.x * BIN_CHUNK;
        int bl[EPT];  // (bucket<<13) | local_rank, or -1
        int vp[EPT];  // packed payload ((dst&127)<<17 | src)
#pragma unroll
        for (int i = 0; i < EPT; ++i) {
            const int e = base + i * 256 + tid;
            if (e < N_EDGES) {
                const int d = dst[e];
                const int b = d >> 7;
                const int lpos = atomicAdd(&cnt[b], 1);
                bl[i] = (b << 13) | lpos;
                vp[i] = ((d & 127) << 17) | src[e];
            } else {
                bl[i] = -1;
            }
        }
        __syncthreads();
        for (int i = tid; i < NB; i += 256) {
            const int c = cnt[i];
            gbase[i] = c ? (i * CAP + atomicAdd(&bcur[i], c)) : 0;
        }
        __syncthreads();
#pragma unroll
        for (int i = 0; i < EPT; ++i) {
            if (bl[i] >= 0) {
                const int b = bl[i] >> 13, lpos = bl[i] & 8191;
                pairs[gbase[b] + lpos] = vp[i];
            }
        }
    }
}

// ---------------------------------------------------------------------------
// Per-bucket counting sort -> per-node CSR segments (within static windows).
// csr entries are BYTE offsets of the src row (src*128) to minimize the
// gather address path. Emits per-node {beg,end}.
// ---------------------------------------------------------------------------
__global__ __launch_bounds__(256) void sort2_kernel(const int* __restrict__ pairs,
                                                    const int* __restrict__ bcur,
                                                    int* __restrict__ csr,
                                                    int2* __restrict__ nseg) {
    __shared__ int cnt[NPB];
    __shared__ int cur[NPB];
    __shared__ int wtot;
    const int b = blockIdx.x;
    const int t = threadIdx.x;
    const int beg = b * CAP;
    const int end = beg + bcur[b];
    if (t < NPB) cnt[t] = 0;
    __syncthreads();
    for (int i = beg + t; i < end; i += 256)
        atomicAdd(&cnt[pairs[i] >> 17], 1);
    __syncthreads();
    int v = 0, x = 0;
    const int lane = t & 63, w = t >> 6;
    if (t < NPB) {
        v = cnt[t];
        x = v;
#pragma unroll
        for (int off = 1; off < 64; off <<= 1) {
            int y = __shfl_up(x, off);
            if (lane >= off) x += y;
        }
        if (t == 63) wtot = x;
    }
    __syncthreads();
    if (t < NPB) {
        const int gp = beg + (x - v) + (w ? wtot : 0);
        cur[t] = gp;
        nseg[b * NPB + t] = make_int2(gp, gp + v);
    }
    __syncthreads();
    for (int i = beg + t; i < end; i += 256) {
        const int p = pairs[i];
        const int pos = atomicAdd(&cur[p >> 17], 1);
        csr[pos] = (p & 0x1FFFF) << 7;  // byte offset of the src row
    }
}

// ---------------------------------------------------------------------------
// Pair-gather core: one wave covers TWO edges per load round.
// lanes 0-31 read row csr[i] (hi=0), lanes 32-63 read row csr[i+1] (hi=1);
// each lane loads a uint = 2 bf16 at columns {2cp, 2cp+1}. bf2f is one
// shift + one and per pair. Caller merges halves with shfl_xor(32).
// acc.x = col 2cp partial, acc.y = col 2cp+1 partial.
// ---------------------------------------------------------------------------
__device__ __forceinline__ float2 gather_pairs(const char* __restrict__ hb,
                                               const int* __restrict__ csr,
                                               int beg, int end, int hi, int cp4) {
    float ax = 0.f, ay = 0.f;
    int i = beg;
#define LOADU(k) const unsigned u##k = *(const unsigned*)(hb + (unsigned)(csr[i + 2*(k) + hi] + cp4))
#define ACCU(k)                                            \
    ax += __uint_as_float(u##k << 16);                     \
    ay += __uint_as_float(u##k & 0xFFFF0000u)
    for (; i + 16 <= end; i += 16) {  // 8 pair-rounds = 16 edges
        LOADU(0); LOADU(1); LOADU(2); LOADU(3);
        LOADU(4); LOADU(5); LOADU(6); LOADU(7);
        ACCU(0); ACCU(1); ACCU(2); ACCU(3);
        ACCU(4); ACCU(5); ACCU(6); ACCU(7);
    }
    if (i + 8 <= end) {
        LOADU(0); LOADU(1); LOADU(2); LOADU(3);
        ACCU(0); ACCU(1); ACCU(2); ACCU(3);
        i += 8;
    }
    if (i + 4 <= end) {
        LOADU(0); LOADU(1);
        ACCU(0); ACCU(1);
        i += 4;
    }
    for (; i < end; i += 2) {
        if (i + hi < end) {
            const unsigned u = *(const unsigned*)(hb + (unsigned)(csr[i + hi] + cp4));
            ax += __uint_as_float(u << 16);
            ay += __uint_as_float(u & 0xFFFF0000u);
        }
    }
#undef LOADU
#undef ACCU
    return make_float2(ax, ay);
}

// ---------------------------------------------------------------------------
// Layer-1 fused: agg(h1) -> rrelu -> @w2 -> bf16 h2. One wave per node.
// ---------------------------------------------------------------------------
__global__ __launch_bounds__(256) void agg_gemm2_kernel(const ushort* __restrict__ h,
                                                        const int* __restrict__ csr,
                                                        const int2* __restrict__ nseg,
                                                        const float* __restrict__ w2,
                                                        ushort* __restrict__ h2) {
    __shared__ float w[OUT_FEAT * OUT_FEAT];  // 16 KB
    __shared__ float rowbuf[4][OUT_FEAT];     // 1 KB, one row per wave
    const int tid = threadIdx.x;

    const float4* w4g = (const float4*)w2;
    float4* wl = (float4*)w;
#pragma unroll
    for (int i = 0; i < 4; ++i) wl[tid + i * 256] = w4g[tid + i * 256];
    __syncthreads();  // w staged (only cross-wave dependency)

    const int wv = tid >> 6, c = tid & 63;
    const int hi = (tid >> 5) & 1, cp = tid & 31;
    const int node = blockIdx.x * 4 + wv;  // grid = 25000, all valid
    const int2 seg = nseg[node];

    float2 acc = gather_pairs((const char*)h, csr, seg.x, seg.y, hi, cp * 4);
    acc.x += __shfl_xor(acc.x, 32);
    acc.y += __shfl_xor(acc.y, 32);
    acc.x = acc.x >= 0.f ? acc.x : acc.x * SLOPE;
    acc.y = acc.y >= 0.f ? acc.y : acc.y * SLOPE;

    // stage the node's row (intra-wave only; no block barrier needed)
    if (hi == 0) ((float2*)rowbuf[wv])[cp] = acc;

    float o = 0.f;
    const float4* rb4 = (const float4*)rowbuf[wv];
#pragma unroll
    for (int k = 0; k < OUT_FEAT; k += 4) {
        const float4 r = rb4[k >> 2];  // wave-uniform broadcast
        o += r.x * w[(k + 0) * OUT_FEAT + c] + r.y * w[(k + 1) * OUT_FEAT + c] +
             r.z * w[(k + 2) * OUT_FEAT + c] + r.w * w[(k + 3) * OUT_FEAT + c];
    }
    h2[(size_t)node * OUT_FEAT + c] = f2bf(o);
}

// ---------------------------------------------------------------------------
// Layer-2 aggregation + fused rrelu -> f32 d_out. One wave per node.
// ---------------------------------------------------------------------------
__global__ __launch_bounds__(256) void agg_rrelu_kernel(const ushort* __restrict__ h,
                                                        const int* __restrict__ csr,
                                                        const int2* __restrict__ nseg,
                                                        float* __restrict__ out) {
    const int tid = threadIdx.x;
    const int hi = (tid >> 5) & 1, cp = tid & 31;
    const int node = blockIdx.x * 4 + (tid >> 6);
    const int2 seg = nseg[node];

    float2 acc = gather_pairs((const char*)h, csr, seg.x, seg.y, hi, cp * 4);
    acc.x += __shfl_xor(acc.x, 32);
    acc.y += __shfl_xor(acc.y, 32);
    if (hi == 0) {
        acc.x = acc.x >= 0.f ? acc.x : acc.x * SLOPE;
        acc.y = acc.y >= 0.f ? acc.y : acc.y * SLOPE;
        ((float2*)(out + (size_t)node * OUT_FEAT))[cp] = acc;
    }
}

extern "C" void kernel_launch(void* const* d_in, const int* in_sizes, int n_in,
                              void* d_out, int out_size, void* d_ws, size_t ws_size,
                              hipStream_t stream) {
    const float* feat = (const float*)d_in[0];
    const int*   src  = (const int*)d_in[1];
    const int*   dst  = (const int*)d_in[2];
    const float* w1   = (const float*)d_in[3];
    const float* w2   = (const float*)d_in[4];
    float* out = (float*)d_out;

    // workspace layout (pairs aliases h2: pairs is dead before h2 is written)
    ushort* h1   = (ushort*)d_ws;                             // 12.8 MB
    ushort* h2   = h1 + (size_t)N_NODES * OUT_FEAT;           // 12.8 MB
    int*    pairs = (int*)h2;                                 // 8.0 MB (alias)
    int*    csr  = (int*)(h2 + (size_t)N_NODES * OUT_FEAT);   // NB*CAP = 8.0 MB
    int2*   nseg = (int2*)(csr + NB * CAP);                   // 0.8 MB
    int*    bcur = (int*)(nseg + NB * NPB);                   // NB

    // ---- build CSR + gemm1 (independent; fused fat kernel) ----
    hipMemsetAsync(bcur, 0, NB * sizeof(int), stream);
    gemm1_binning_kernel<<<BIN_BLOCKS + GEMM1_BLOCKS, 256, 0, stream>>>(
        feat, w1, h1, src, dst, bcur, pairs);
    sort2_kernel<<<NB, 256, 0, stream>>>(pairs, bcur, csr, nseg);

    // ---- layer 1 (gemm2 fused into aggregation) ----
    agg_gemm2_kernel<<<N_NODES / 4, 256, 0, stream>>>(h1, csr, nseg, w2, h2);

    // ---- layer 2 ----
    agg_rrelu_kernel<<<N_NODES / 4, 256, 0, stream>>>(h2, csr, nseg, out);
}

// Round 10
// 167.490 us; speedup vs baseline: 1.5405x; 1.0434x over previous
//
#include <hip/hip_runtime.h>

#define N_NODES 100000
#define N_EDGES 1600000
#define IN_FEAT 128
#define OUT_FEAT 64
#define SLOPE 0.22916666666666666f  // (1/8 + 1/3)/2 = 11/48

#define NPB 128            // nodes per bucket
#define NB 782             // ceil(N_NODES / NPB)
#define CAP 2560           // static bucket capacity (mean 2046 -> 11+ sigma margin)
#define BIN_CHUNK 8192     // edges per binning block
#define EPT 32             // edges per thread in binning (BIN_CHUNK/256)
#define BIN_BLOCKS ((N_EDGES + BIN_CHUNK - 1) / BIN_CHUNK)  // 196
#define GEMM1_BLOCKS (N_NODES / 16)                         // 6250

__device__ __forceinline__ ushort f2bf(float x) {
    unsigned u = __float_as_uint(x);
    u += 0x7FFFu + ((u >> 16) & 1u);  // round to nearest even
    return (ushort)(u >> 16);
}

// ---------------------------------------------------------------------------
// Fat kernel: blocks [0, BIN_BLOCKS) do edge binning; the rest do gemm1.
// gemm1 layout: 256 threads = 64 cols x 4 k-slices; w1 column-slice lives in
// 32 REGISTERS per thread (no LDS w traffic); feat rows are LDS broadcast
// b128 reads; 4 k-slice partials reduced through LDS.
// ---------------------------------------------------------------------------
union FatSmem {
    struct { float f[16 * IN_FEAT]; float part[4 * 16 * OUT_FEAT]; } g;  // 8+16 KB
    struct { int cnt[NB]; int gbase[NB]; } b;                            // 6.3 KB
};

__global__ __launch_bounds__(256) void gemm1_binning_kernel(
        const float* __restrict__ feat, const float* __restrict__ w1,
        ushort* __restrict__ h1,
        const int* __restrict__ src, const int* __restrict__ dst,
        int* __restrict__ bcur, int* __restrict__ pairs) {
    __shared__ FatSmem s;
    const int tid = threadIdx.x;

    if (blockIdx.x >= BIN_BLOCKS) {
        // ---------------- gemm1: feat[16 rows] @ w1 -> bf16 h1 ----------------
        const int c = tid & 63;   // output column
        const int ks = tid >> 6;  // k-slice (32 k each)

        // w1 column c, k-slice ks -> 32 registers (coalesced 256B per j)
        float wr[32];
#pragma unroll
        for (int j = 0; j < 32; ++j)
            wr[j] = w1[(ks * 32 + j) * OUT_FEAT + c];

        // stage 16 feat rows (f32) in LDS
        const int row0 = (blockIdx.x - BIN_BLOCKS) * 16;
        const float4* fg = (const float4*)(feat + (size_t)row0 * IN_FEAT);
        float4* fl = (float4*)s.g.f;
        fl[tid] = fg[tid];
        fl[tid + 256] = fg[tid + 256];
        __syncthreads();

        float acc[16];
#pragma unroll
        for (int r = 0; r < 16; ++r) acc[r] = 0.f;

        const float4* fv = (const float4*)s.g.f;
#pragma unroll
        for (int j4 = 0; j4 < 8; ++j4) {
            const float wa = wr[4 * j4], wb = wr[4 * j4 + 1];
            const float wc = wr[4 * j4 + 2], wd = wr[4 * j4 + 3];
#pragma unroll
            for (int r = 0; r < 16; ++r) {
                const float4 a = fv[r * 32 + ks * 8 + j4];  // wave-broadcast
                acc[r] += a.x * wa + a.y * wb + a.z * wc + a.w * wd;
            }
        }

        // k-slice partials -> LDS, reduce, bf16 store
#pragma unroll
        for (int r = 0; r < 16; ++r)
            s.g.part[ks * (16 * OUT_FEAT) + r * OUT_FEAT + c] = acc[r];
        __syncthreads();

        ushort2* h1u2 = (ushort2*)h1;
#pragma unroll
        for (int half = 0; half < 2; ++half) {
            const int idx = half * 256 + tid;   // 512 ushort2 outputs
            const int r = idx >> 5;             // 0..15
            const int cp = idx & 31;            // ushort2 column pair
            const float* p = s.g.part + r * OUT_FEAT + 2 * cp;
            const float lo = p[0] + p[1024] + p[2048] + p[3072];
            const float hi = p[1] + p[1025] + p[2049] + p[3073];
            h1u2[(size_t)(row0 + r) * 32 + cp] = make_ushort2(f2bf(lo), f2bf(hi));
        }
    } else {
        // ---------------- binning: dense per-block runs per bucket ----------------
        int* cnt = s.b.cnt;
        int* gbase = s.b.gbase;
        for (int i = tid; i < NB; i += 256) cnt[i] = 0;
        __syncthreads();
        const int base = blockIdx.x * BIN_CHUNK;
        int bl[EPT];  // (bucket<<13) | local_rank, or -1
        int vp[EPT];  // packed payload ((dst&127)<<17 | src)
#pragma unroll
        for (int i = 0; i < EPT; ++i) {
            const int e = base + i * 256 + tid;
            if (e < N_EDGES) {
                const int d = dst[e];
                const int b = d >> 7;
                const int lpos = atomicAdd(&cnt[b], 1);
                bl[i] = (b << 13) | lpos;
                vp[i] = ((d & 127) << 17) | src[e];
            } else {
                bl[i] = -1;
            }
        }
        __syncthreads();
        for (int i = tid; i < NB; i += 256) {
            const int cc = cnt[i];
            gbase[i] = cc ? (i * CAP + atomicAdd(&bcur[i], cc)) : 0;
        }
        __syncthreads();
#pragma unroll
        for (int i = 0; i < EPT; ++i) {
            if (bl[i] >= 0) {
                const int b = bl[i] >> 13, lpos = bl[i] & 8191;
                pairs[gbase[b] + lpos] = vp[i];
            }
        }
    }
}

// ---------------------------------------------------------------------------
// Per-bucket counting sort -> per-node CSR segments (within static windows).
// csr entries are BYTE offsets of the src row (src*128).
// ---------------------------------------------------------------------------
__global__ __launch_bounds__(256) void sort2_kernel(const int* __restrict__ pairs,
                                                    const int* __restrict__ bcur,
                                                    int* __restrict__ csr,
                                                    int2* __restrict__ nseg) {
    __shared__ int cnt[NPB];
    __shared__ int cur[NPB];
    __shared__ int wtot;
    const int b = blockIdx.x;
    const int t = threadIdx.x;
    const int beg = b * CAP;
    const int end = beg + bcur[b];
    if (t < NPB) cnt[t] = 0;
    __syncthreads();
    for (int i = beg + t; i < end; i += 256)
        atomicAdd(&cnt[pairs[i] >> 17], 1);
    __syncthreads();
    int v = 0, x = 0;
    const int lane = t & 63, w = t >> 6;
    if (t < NPB) {
        v = cnt[t];
        x = v;
#pragma unroll
        for (int off = 1; off < 64; off <<= 1) {
            int y = __shfl_up(x, off);
            if (lane >= off) x += y;
        }
        if (t == 63) wtot = x;
    }
    __syncthreads();
    if (t < NPB) {
        const int gp = beg + (x - v) + (w ? wtot : 0);
        cur[t] = gp;
        nseg[b * NPB + t] = make_int2(gp, gp + v);
    }
    __syncthreads();
    for (int i = beg + t; i < end; i += 256) {
        const int p = pairs[i];
        const int pos = atomicAdd(&cur[p >> 17], 1);
        csr[pos] = (p & 0x1FFFF) << 7;  // byte offset of the src row
    }
}

// ---------------------------------------------------------------------------
// Pair-gather core (wave-uniform csr indices -> scalar loads after
// readfirstlane on the segment bounds). lanes 0-31 read row csr[i],
// lanes 32-63 read row csr[i+1]; each lane loads a uint = 2 bf16 columns.
// ---------------------------------------------------------------------------
__device__ __forceinline__ float2 gather_pairs(const char* __restrict__ hb,
                                               const int* __restrict__ csr,
                                               int beg, int end, int hi, int cp4) {
    float ax = 0.f, ay = 0.f;
    int i = beg;
#define LOADU(k) const unsigned u##k = *(const unsigned*)(hb + (unsigned)(csr[i + 2*(k) + hi] + cp4))
#define ACCU(k)                                            \
    ax += __uint_as_float(u##k << 16);                     \
    ay += __uint_as_float(u##k & 0xFFFF0000u)
    for (; i + 16 <= end; i += 16) {  // 8 pair-rounds = 16 edges
        LOADU(0); LOADU(1); LOADU(2); LOADU(3);
        LOADU(4); LOADU(5); LOADU(6); LOADU(7);
        ACCU(0); ACCU(1); ACCU(2); ACCU(3);
        ACCU(4); ACCU(5); ACCU(6); ACCU(7);
    }
    if (i + 8 <= end) {
        LOADU(0); LOADU(1); LOADU(2); LOADU(3);
        ACCU(0); ACCU(1); ACCU(2); ACCU(3);
        i += 8;
    }
    if (i + 4 <= end) {
        LOADU(0); LOADU(1);
        ACCU(0); ACCU(1);
        i += 4;
    }
    for (; i < end; i += 2) {
        if (i + hi < end) {
            const unsigned u = *(const unsigned*)(hb + (unsigned)(csr[i + hi] + cp4));
            ax += __uint_as_float(u << 16);
            ay += __uint_as_float(u & 0xFFFF0000u);
        }
    }
#undef LOADU
#undef ACCU
    return make_float2(ax, ay);
}

// ---------------------------------------------------------------------------
// Layer-1 fused: agg(h1) -> rrelu -> @w2 -> bf16 h2. One wave per node.
// ---------------------------------------------------------------------------
__global__ __launch_bounds__(256) void agg_gemm2_kernel(const ushort* __restrict__ h,
                                                        const int* __restrict__ csr,
                                                        const int2* __restrict__ nseg,
                                                        const float* __restrict__ w2,
                                                        ushort* __restrict__ h2) {
    __shared__ float w[OUT_FEAT * OUT_FEAT];  // 16 KB
    __shared__ float rowbuf[4][OUT_FEAT];     // 1 KB, one row per wave
    const int tid = threadIdx.x;

    const float4* w4g = (const float4*)w2;
    float4* wl = (float4*)w;
#pragma unroll
    for (int i = 0; i < 4; ++i) wl[tid + i * 256] = w4g[tid + i * 256];
    __syncthreads();  // w staged (only cross-wave dependency)

    const int wv = tid >> 6, c = tid & 63;
    const int hi = (tid >> 5) & 1, cp = tid & 31;
    const int node = blockIdx.x * 4 + wv;  // grid = 25000, all valid
    const int2 seg = nseg[node];
    const int beg = __builtin_amdgcn_readfirstlane(seg.x);
    const int end = __builtin_amdgcn_readfirstlane(seg.y);

    float2 acc = gather_pairs((const char*)h, csr, beg, end, hi, cp * 4);
    acc.x += __shfl_xor(acc.x, 32);
    acc.y += __shfl_xor(acc.y, 32);
    acc.x = acc.x >= 0.f ? acc.x : acc.x * SLOPE;
    acc.y = acc.y >= 0.f ? acc.y : acc.y * SLOPE;

    // stage the node's row (intra-wave only; no block barrier needed)
    if (hi == 0) ((float2*)rowbuf[wv])[cp] = acc;

    float o = 0.f;
    const float4* rb4 = (const float4*)rowbuf[wv];
#pragma unroll
    for (int k = 0; k < OUT_FEAT; k += 4) {
        const float4 r = rb4[k >> 2];  // wave-uniform broadcast
        o += r.x * w[(k + 0) * OUT_FEAT + c] + r.y * w[(k + 1) * OUT_FEAT + c] +
             r.z * w[(k + 2) * OUT_FEAT + c] + r.w * w[(k + 3) * OUT_FEAT + c];
    }
    h2[(size_t)node * OUT_FEAT + c] = f2bf(o);
}

// ---------------------------------------------------------------------------
// Layer-2 aggregation + fused rrelu -> f32 d_out. One wave per node.
// ---------------------------------------------------------------------------
__global__ __launch_bounds__(256) void agg_rrelu_kernel(const ushort* __restrict__ h,
                                                        const int* __restrict__ csr,
                                                        const int2* __restrict__ nseg,
                                                        float* __restrict__ out) {
    const int tid = threadIdx.x;
    const int hi = (tid >> 5) & 1, cp = tid & 31;
    const int node = blockIdx.x * 4 + (tid >> 6);
    const int2 seg = nseg[node];
    const int beg = __builtin_amdgcn_readfirstlane(seg.x);
    const int end = __builtin_amdgcn_readfirstlane(seg.y);

    float2 acc = gather_pairs((const char*)h, csr, beg, end, hi, cp * 4);
    acc.x += __shfl_xor(acc.x, 32);
    acc.y += __shfl_xor(acc.y, 32);
    if (hi == 0) {
        acc.x = acc.x >= 0.f ? acc.x : acc.x * SLOPE;
        acc.y = acc.y >= 0.f ? acc.y : acc.y * SLOPE;
        ((float2*)(out + (size_t)node * OUT_FEAT))[cp] = acc;
    }
}

extern "C" void kernel_launch(void* const* d_in, const int* in_sizes, int n_in,
                              void* d_out, int out_size, void* d_ws, size_t ws_size,
                              hipStream_t stream) {
    const float* feat = (const float*)d_in[0];
    const int*   src  = (const int*)d_in[1];
    const int*   dst  = (const int*)d_in[2];
    const float* w1   = (const float*)d_in[3];
    const float* w2   = (const float*)d_in[4];
    float* out = (float*)d_out;

    // workspace layout (pairs aliases h2: pairs is dead before h2 is written)
    ushort* h1   = (ushort*)d_ws;                             // 12.8 MB
    ushort* h2   = h1 + (size_t)N_NODES * OUT_FEAT;           // 12.8 MB
    int*    pairs = (int*)h2;                                 // 8.0 MB (alias)
    int*    csr  = (int*)(h2 + (size_t)N_NODES * OUT_FEAT);   // NB*CAP = 8.0 MB
    int2*   nseg = (int2*)(csr + NB * CAP);                   // 0.8 MB
    int*    bcur = (int*)(nseg + NB * NPB);                   // NB

    // ---- build CSR + gemm1 (independent; fused fat kernel) ----
    hipMemsetAsync(bcur, 0, NB * sizeof(int), stream);
    gemm1_binning_kernel<<<BIN_BLOCKS + GEMM1_BLOCKS, 256, 0, stream>>>(
        feat, w1, h1, src, dst, bcur, pairs);
    sort2_kernel<<<NB, 256, 0, stream>>>(pairs, bcur, csr, nseg);

    // ---- layer 1 (gemm2 fused into aggregation) ----
    agg_gemm2_kernel<<<N_NODES / 4, 256, 0, stream>>>(h1, csr, nseg, w2, h2);

    // ---- layer 2 ----
    agg_rrelu_kernel<<<N_NODES / 4, 256, 0, stream>>>(h2, csr, nseg, out);
}